// Round 2
// baseline (1378.275 us; speedup 1.0000x reference)
//
#include <hip/hip_runtime.h>

#define HW 65536
#define CDIM 64
#define PST 264   // P region row stride (u16 elems); 264*2B=528B -> uniform bank spread

typedef __attribute__((ext_vector_type(8))) short bf16x8;
typedef __attribute__((ext_vector_type(4))) float f32x4;
typedef __attribute__((ext_vector_type(4))) unsigned short u16x4;
typedef __attribute__((ext_vector_type(8))) unsigned short u16x8;

__device__ __forceinline__ unsigned short f2bf(float x) {
    union { float f; unsigned u; } v; v.f = x;
    unsigned r = v.u + 0x7fffu + ((v.u >> 16) & 1u);
    return (unsigned short)(r >> 16);
}
__device__ __forceinline__ float bf2f(unsigned short u) {
    union { unsigned u; float f; } v; v.u = ((unsigned)u) << 16; return v.f;
}

// ---------------- Pass 1: projection O[c][pix] = sum_i W[c][i] X[i][pix] + b[c] ----------------
// 256 thr: tc=t>>5 (8 c-groups of 8), tp=t&31 (32 pix-groups of 8). 8x8 register tile.
// W transposed into LDS (b128 reads, 2 uniform addrs/wave); X via coalesced global float4 (L1 reuse 8x).
__global__ __launch_bounds__(256, 4)
void proj_kernel(const float* __restrict__ x, const float* __restrict__ w,
                 const float* __restrict__ bias, unsigned short* __restrict__ o) {
    __shared__ float WT[64 * 68];
    const int t = threadIdx.x;
    const int slice = blockIdx.y;
    const int pixbase = blockIdx.x * 256;
    const int tc = t >> 5, tp = t & 31;
    const int c0 = tc * 8, p0 = pixbase + tp * 8;

#pragma unroll
    for (int it = 0; it < 16; ++it) {
        int idx = it * 256 + t;           // idx = c*64 + i
        int c = idx >> 6, i = idx & 63;
        WT[i * 68 + c] = w[idx];
    }
    __syncthreads();

    const float* xb = x + (size_t)slice * CDIM * HW;
    float acc[8][8];
#pragma unroll
    for (int cc = 0; cc < 8; ++cc) {
        float b = bias[c0 + cc];
#pragma unroll
        for (int pp = 0; pp < 8; ++pp) acc[cc][pp] = b;
    }

#pragma unroll 2
    for (int i = 0; i < 64; ++i) {
        f32x4 x0 = *(const f32x4*)&xb[(size_t)i * HW + p0];
        f32x4 x1 = *(const f32x4*)&xb[(size_t)i * HW + p0 + 4];
        f32x4 w0 = *(const f32x4*)&WT[i * 68 + c0];
        f32x4 w1 = *(const f32x4*)&WT[i * 68 + c0 + 4];
#pragma unroll
        for (int cc = 0; cc < 4; ++cc) {
#pragma unroll
            for (int pp = 0; pp < 4; ++pp) {
                acc[cc][pp]     = fmaf(w0[cc], x0[pp], acc[cc][pp]);
                acc[cc][pp + 4] = fmaf(w0[cc], x1[pp], acc[cc][pp + 4]);
                acc[cc + 4][pp]     = fmaf(w1[cc], x0[pp], acc[cc + 4][pp]);
                acc[cc + 4][pp + 4] = fmaf(w1[cc], x1[pp], acc[cc + 4][pp + 4]);
            }
        }
    }

    unsigned short* ob = o + (size_t)slice * CDIM * HW;
#pragma unroll
    for (int cc = 0; cc < 8; ++cc) {
        u16x4 lo, hi;
#pragma unroll
        for (int e = 0; e < 4; ++e) { lo[e] = f2bf(acc[cc][e]); hi[e] = f2bf(acc[cc][e + 4]); }
        size_t ob2 = (size_t)(c0 + cc) * HW + p0;
        *(u16x4*)&ob[ob2] = lo;
        *(u16x4*)&ob[ob2 + 4] = hi;
    }
}

// ---------------- Pass 1.5: 256x256 bf16 transpose (per slice), 64x64 tiles ----------------
__global__ __launch_bounds__(256)
void transpose_kernel(const unsigned short* __restrict__ src, unsigned short* __restrict__ dst) {
    __shared__ unsigned short T[64 * 72];
    const int t = threadIdx.x;
    const int sl = blockIdx.y;
    const int th = blockIdx.x >> 2, tw = blockIdx.x & 3;

    const unsigned short* s = src + (size_t)sl * HW + th * 64 * 256 + tw * 64;
#pragma unroll
    for (int it = 0; it < 2; ++it) {
        int cc = t + it * 256;
        int r = cc >> 3, j = cc & 7;
        *(bf16x8*)&T[r * 72 + j * 8] = *(const bf16x8*)&s[r * 256 + j * 8];
    }
    __syncthreads();
    unsigned short* d = dst + (size_t)sl * HW + tw * 64 * 256 + th * 64;
#pragma unroll
    for (int it = 0; it < 2; ++it) {
        int cc = t + it * 256;
        int w = cc >> 3, j = cc & 7;
        bf16x8 val;
#pragma unroll
        for (int e = 0; e < 8; ++e) val[e] = (short)T[(j * 8 + e) * 72 + w];
        *(bf16x8*)&d[w * 256 + j * 8] = val;
    }
}

// ---------------- Pass 2: fused dual attention per (b,c) ----------------
// 512 thr = 8 waves, grid 4(wc: col band) x 2(wr) with rt in {0,1}: row band = (wr*2+rt)*64.
// Both attentions computed in transposed orientation -> shared persistent oaccT[x][h].
// S written to LDS as exp(score) unnormalized (no-max softmax: scores ~N(0,1), |s|<~20),
// normalized by a vectorized LDS sweep, then PV with A-or-B frags from LDS (b128) / global.
__global__ __launch_bounds__(512, 2)
void attn_kernel(const unsigned short* __restrict__ q,  const unsigned short* __restrict__ qT,
                 const unsigned short* __restrict__ v,  const unsigned short* __restrict__ vT,
                 const unsigned short* __restrict__ kk, const unsigned short* __restrict__ kT,
                 const float* __restrict__ mainx, float* __restrict__ out) {
    __shared__ unsigned short P[256 * PST];   // 135168 B
    __shared__ float stats[256 * 4];          // 4096 B
    __shared__ float invbuf[264];             // 1056 B

    const int t = threadIdx.x;
    const int wave = t >> 6, lane = t & 63;
    const int quad = lane >> 4, l16 = lane & 15;
    const int wr = wave >> 2, wc = wave & 3;
    const int h0 = wc * 64;
    const int bc = blockIdx.x;

    const unsigned short* Q  = q  + (size_t)bc * HW;
    const unsigned short* QT = qT + (size_t)bc * HW;
    const unsigned short* V  = v  + (size_t)bc * HW;
    const unsigned short* VT = vT + (size_t)bc * HW;

    f32x4 oacc[2][4][4];
#pragma unroll
    for (int rt = 0; rt < 2; ++rt)
#pragma unroll
        for (int mt = 0; mt < 4; ++mt)
#pragma unroll
            for (int nt = 0; nt < 4; ++nt) oacc[rt][mt][nt] = (f32x4){0.f, 0.f, 0.f, 0.f};

    for (int n = 0; n < 4; ++n) {
        const unsigned short* K  = kk + ((size_t)(n * 256 + bc)) * HW;
        const unsigned short* KT = kT + ((size_t)(n * 256 + bc)) * HW;

        // ================= TIME: S1T[g][h] = sum_w K[g][w] Q[h][w] ; softmax over g =========
        __syncthreads();                      // P free (prev PV done)
        for (int rt = 0; rt < 2; ++rt) {
            const int band = (wr * 2 + rt) * 64;
            f32x4 s[4][4];
#pragma unroll
            for (int mt = 0; mt < 4; ++mt)
#pragma unroll
                for (int nt = 0; nt < 4; ++nt) s[mt][nt] = (f32x4){0.f, 0.f, 0.f, 0.f};
            for (int ks = 0; ks < 8; ++ks) {
                bf16x8 a[4], bb[4];
#pragma unroll
                for (int mt = 0; mt < 4; ++mt)
                    a[mt] = *(const bf16x8*)&K[(band + mt * 16 + l16) * 256 + ks * 32 + quad * 8];
#pragma unroll
                for (int nt = 0; nt < 4; ++nt)
                    bb[nt] = *(const bf16x8*)&Q[(h0 + nt * 16 + l16) * 256 + ks * 32 + quad * 8];
#pragma unroll
                for (int mt = 0; mt < 4; ++mt)
#pragma unroll
                    for (int nt = 0; nt < 4; ++nt)
                        s[mt][nt] = __builtin_amdgcn_mfma_f32_16x16x32_bf16(a[mt], bb[nt], s[mt][nt], 0, 0, 0);
            }
            // exp (no-max), write P1[h][g] (u16x4 over r), per-column partial sums
            float csum[4] = {0.f, 0.f, 0.f, 0.f};
#pragma unroll
            for (int mt = 0; mt < 4; ++mt)
#pragma unroll
                for (int nt = 0; nt < 4; ++nt) {
                    u16x4 pk;
#pragma unroll
                    for (int r = 0; r < 4; ++r) {
                        float e = __expf(s[mt][nt][r] * 0.0625f);
                        pk[r] = f2bf(e); csum[nt] += e;
                    }
                    *(u16x4*)&P[(h0 + nt * 16 + l16) * PST + band + mt * 16 + quad * 4] = pk;
                }
#pragma unroll
            for (int nt = 0; nt < 4; ++nt) {
                csum[nt] += __shfl_xor(csum[nt], 16);
                csum[nt] += __shfl_xor(csum[nt], 32);
            }
            if (quad == 0) {
#pragma unroll
                for (int nt = 0; nt < 4; ++nt)
                    stats[(h0 + nt * 16 + l16) * 4 + wr * 2 + rt] = csum[nt];
            }
        }
        __syncthreads();
        if (t < 256) {
            f32x4 s4 = *(f32x4*)&stats[t * 4];
            invbuf[t] = 1.f / (s4[0] + s4[1] + s4[2] + s4[3]);
        }
        __syncthreads();
        // renorm sweep: factor per row h
        for (int cc = 0; cc < 17; ++cc) {
            int idx = cc * 512 + t;
            if (idx < 8448) {
                int row = idx / 33;
                int off = idx - row * 33;
                unsigned short* pp = &P[row * PST + off * 8];
                u16x8 a8 = *(u16x8*)pp;
                float f = invbuf[row];
#pragma unroll
                for (int e = 0; e < 8; ++e) a8[e] = f2bf(bf2f(a8[e]) * f);
                *(u16x8*)pp = a8;
            }
        }
        __syncthreads();
        // PV-T: out1T[x=w][h] += sum_g VT[w][g] * P1[h][g]
        for (int ks = 0; ks < 8; ++ks) {
            bf16x8 bb[4];
#pragma unroll
            for (int nt = 0; nt < 4; ++nt)
                bb[nt] = *(const bf16x8*)&P[(h0 + nt * 16 + l16) * PST + ks * 32 + quad * 8];
#pragma unroll
            for (int rt = 0; rt < 2; ++rt) {
                const int band = (wr * 2 + rt) * 64;
                bf16x8 a[4];
#pragma unroll
                for (int mt = 0; mt < 4; ++mt)
                    a[mt] = *(const bf16x8*)&VT[(band + mt * 16 + l16) * 256 + ks * 32 + quad * 8];
#pragma unroll
                for (int mt = 0; mt < 4; ++mt)
#pragma unroll
                    for (int nt = 0; nt < 4; ++nt)
                        oacc[rt][mt][nt] = __builtin_amdgcn_mfma_f32_16x16x32_bf16(a[mt], bb[nt], oacc[rt][mt][nt], 0, 0, 0);
            }
        }

        // ================= SPACE: S2[w][v] = sum_h QT[w][h] KT[v][h] ; softmax over v ======
        __syncthreads();                      // P1 consumed
        for (int rt = 0; rt < 2; ++rt) {
            const int band = (wr * 2 + rt) * 64;
            f32x4 s[4][4];
#pragma unroll
            for (int mt = 0; mt < 4; ++mt)
#pragma unroll
                for (int nt = 0; nt < 4; ++nt) s[mt][nt] = (f32x4){0.f, 0.f, 0.f, 0.f};
            for (int ks = 0; ks < 8; ++ks) {
                bf16x8 a[4], bb[4];
#pragma unroll
                for (int mt = 0; mt < 4; ++mt)
                    a[mt] = *(const bf16x8*)&QT[(band + mt * 16 + l16) * 256 + ks * 32 + quad * 8];
#pragma unroll
                for (int nt = 0; nt < 4; ++nt)
                    bb[nt] = *(const bf16x8*)&KT[(h0 + nt * 16 + l16) * 256 + ks * 32 + quad * 8];
#pragma unroll
                for (int mt = 0; mt < 4; ++mt)
#pragma unroll
                    for (int nt = 0; nt < 4; ++nt)
                        s[mt][nt] = __builtin_amdgcn_mfma_f32_16x16x32_bf16(a[mt], bb[nt], s[mt][nt], 0, 0, 0);
            }
            // exp, write P2T[v][w] (same addressing pattern), per-row partial sums
            float rsum[4][4];
#pragma unroll
            for (int mt = 0; mt < 4; ++mt)
#pragma unroll
                for (int r = 0; r < 4; ++r) rsum[mt][r] = 0.f;
#pragma unroll
            for (int mt = 0; mt < 4; ++mt)
#pragma unroll
                for (int nt = 0; nt < 4; ++nt) {
                    u16x4 pk;
#pragma unroll
                    for (int r = 0; r < 4; ++r) {
                        float e = __expf(s[mt][nt][r] * 0.0625f);
                        pk[r] = f2bf(e); rsum[mt][r] += e;
                    }
                    *(u16x4*)&P[(h0 + nt * 16 + l16) * PST + band + mt * 16 + quad * 4] = pk;
                }
#pragma unroll
            for (int mt = 0; mt < 4; ++mt)
#pragma unroll
                for (int r = 0; r < 4; ++r) {
                    rsum[mt][r] += __shfl_xor(rsum[mt][r], 1);
                    rsum[mt][r] += __shfl_xor(rsum[mt][r], 2);
                    rsum[mt][r] += __shfl_xor(rsum[mt][r], 4);
                    rsum[mt][r] += __shfl_xor(rsum[mt][r], 8);
                }
            if (l16 == 0) {
#pragma unroll
                for (int mt = 0; mt < 4; ++mt)
#pragma unroll
                    for (int r = 0; r < 4; ++r)
                        stats[(band + mt * 16 + quad * 4 + r) * 4 + wc] = rsum[mt][r];
            }
        }
        __syncthreads();
        if (t < 256) {
            f32x4 s4 = *(f32x4*)&stats[t * 4];
            invbuf[t] = 1.f / (s4[0] + s4[1] + s4[2] + s4[3]);
        }
        __syncthreads();
        // renorm sweep: factor per element (column w of P2T)
        for (int cc = 0; cc < 17; ++cc) {
            int idx = cc * 512 + t;
            if (idx < 8448) {
                int row = idx / 33;
                int off = idx - row * 33;
                unsigned short* pp = &P[row * PST + off * 8];
                u16x8 a8 = *(u16x8*)pp;
                f32x4 f0 = *(f32x4*)&invbuf[off * 8];
                f32x4 f1 = *(f32x4*)&invbuf[off * 8 + 4];
#pragma unroll
                for (int e = 0; e < 4; ++e) {
                    a8[e]     = f2bf(bf2f(a8[e]) * f0[e]);
                    a8[e + 4] = f2bf(bf2f(a8[e + 4]) * f1[e]);
                }
                *(u16x8*)pp = a8;
            }
        }
        __syncthreads();
        // PV-S: out2T[x=v][h] += sum_w P2T[v][w] * V[h][w]
        for (int ks = 0; ks < 8; ++ks) {
            bf16x8 bb[4];
#pragma unroll
            for (int nt = 0; nt < 4; ++nt)
                bb[nt] = *(const bf16x8*)&V[(h0 + nt * 16 + l16) * 256 + ks * 32 + quad * 8];
#pragma unroll
            for (int rt = 0; rt < 2; ++rt) {
                const int band = (wr * 2 + rt) * 64;
                bf16x8 a[4];
#pragma unroll
                for (int mt = 0; mt < 4; ++mt)
                    a[mt] = *(const bf16x8*)&P[(band + mt * 16 + l16) * PST + ks * 32 + quad * 8];
#pragma unroll
                for (int mt = 0; mt < 4; ++mt)
#pragma unroll
                    for (int nt = 0; nt < 4; ++nt)
                        oacc[rt][mt][nt] = __builtin_amdgcn_mfma_f32_16x16x32_bf16(a[mt], bb[nt], oacc[rt][mt][nt], 0, 0, 0);
            }
        }
    }

    // epilogue: out[h][x] = main[h][x] + oaccT[x][h]
    const float* mp = mainx + (size_t)bc * HW;
    float* op = out + (size_t)bc * HW;
#pragma unroll
    for (int rt = 0; rt < 2; ++rt)
#pragma unroll
        for (int mt = 0; mt < 4; ++mt)
#pragma unroll
            for (int nt = 0; nt < 4; ++nt) {
                int xr = (wr * 2 + rt) * 64 + mt * 16 + quad * 4;
                int hh = h0 + nt * 16 + l16;
                f32x4 m4 = *(const f32x4*)&mp[hh * 256 + xr];
                f32x4 o4;
#pragma unroll
                for (int e = 0; e < 4; ++e) o4[e] = m4[e] + oacc[rt][mt][nt][e];
                *(f32x4*)&op[hh * 256 + xr] = o4;
            }
}

// ---------------- launch ----------------

extern "C" void kernel_launch(void* const* d_in, const int* in_sizes, int n_in,
                              void* d_out, int out_size, void* d_ws, size_t ws_size,
                              hipStream_t stream) {
    const float* mainx  = (const float*)d_in[0];
    const float* assist = (const float*)d_in[1];
    const float* wq = (const float*)d_in[2];
    const float* bq = (const float*)d_in[3];
    const float* wk = (const float*)d_in[4];
    const float* bk = (const float*)d_in[5];
    const float* wv = (const float*)d_in[6];
    const float* bv = (const float*)d_in[7];
    float* outp = (float*)d_out;

    unsigned short* ws = (unsigned short*)d_ws;
    const size_t SLICE = (size_t)16777216;          // B*C*H*W elements
    unsigned short* Qw  = ws;
    unsigned short* QTw = ws + SLICE;
    unsigned short* Vw  = ws + 2 * SLICE;
    unsigned short* VTw = ws + 3 * SLICE;
    unsigned short* Kw  = ws + 4 * SLICE;           // N*B*C*H*W = 4*SLICE
    unsigned short* KTw = ws + 8 * SLICE;
    // total: 12 * SLICE * 2 bytes = 402,653,184 bytes

    proj_kernel<<<dim3(256, 4), 256, 0, stream>>>(mainx, wq, bq, Qw);
    proj_kernel<<<dim3(256, 4), 256, 0, stream>>>(mainx, wv, bv, Vw);
    proj_kernel<<<dim3(256, 16), 256, 0, stream>>>(assist, wk, bk, Kw);

    transpose_kernel<<<dim3(16, 256), 256, 0, stream>>>(Qw, QTw);
    transpose_kernel<<<dim3(16, 256), 256, 0, stream>>>(Vw, VTw);
    transpose_kernel<<<dim3(16, 1024), 256, 0, stream>>>(Kw, KTw);

    attn_kernel<<<dim3(256), 512, 0, stream>>>(Qw, QTw, Vw, VTw, Kw, KTw, mainx, outp);
}